// Round 3
// baseline (207.862 us; speedup 1.0000x reference)
//
#include <hip/hip_runtime.h>

// Problem constants (fixed-shape bench)
#define B_ 4
#define K_ 64
#define R_ 16
#define H_ 16
#define S_ 2048
#define ROWS_PER_BLOCK 16
#define NCH 16   // i-chunks for partial reduction
#define IPB 4    // i-rows per chunk (NCH*IPB == K_)

// Native clang vector type: __builtin_nontemporal_store requires a real
// vector type, not HIP's float4 class.
typedef float f32x4 __attribute__((ext_vector_type(4)));

// ---------------------------------------------------------------------------
// Kernel A1: partial reduction over i. Grid (B, NCH), 256 thr.
//   partial[b][ch][q] = sum_{i in chunk} adj[b, i, q/R, q%R],  q = 0..1023
// Each thread owns 4 consecutive q (one float4), reads are 16B/lane coalesced.
// ---------------------------------------------------------------------------
__global__ __launch_bounds__(256) void partial_reduce_kernel(
    const f32x4* __restrict__ adj4,     // [B,K, K*R/4]
    f32x4*       __restrict__ partial4) // [B,NCH, 256]
{
    const int b   = blockIdx.x;
    const int ch  = blockIdx.y;
    const int tid = threadIdx.x;

    const f32x4* base = adj4 + ((size_t)b * K_ + ch * IPB) * (K_ * R_ / 4);
    f32x4 acc = (f32x4)(0.f);
    #pragma unroll
    for (int i = 0; i < IPB; ++i)
        acc += base[i * (K_ * R_ / 4) + tid];
    partial4[((size_t)b * NCH + ch) * 256 + tid] = acc;
}

// ---------------------------------------------------------------------------
// Kernel A2: finalize. Grid B, 256 thr.
//   s[j][r] = sum_ch partial[b][ch][j*R+r]
//   anchor[h][j] = (1/K) * sum_r s[j][r] * W[r][h]
//   colval[b,h,:] = 0; colval[b,h,idx[b,k]] = anchor[h][k], k ascending
//   (serial per head => last-write-wins on duplicates, numpy semantics)
// ---------------------------------------------------------------------------
__global__ __launch_bounds__(256) void finalize_colval_kernel(
    const f32x4* __restrict__ partial4, // [B,NCH,256]
    const float* __restrict__ W,        // [R,H]
    const int*   __restrict__ idx,      // [B,K]
    float*       __restrict__ colval)   // [B,H,S]
{
    __shared__ float s_jr[K_ * R_];      // s[j][r]
    __shared__ float s_anchor[H_ * K_];  // anchor[h][j]
    __shared__ float s_W[R_ * H_];

    const int b   = blockIdx.x;
    const int tid = threadIdx.x;

    if (tid < R_ * H_) s_W[tid] = W[tid];

    // Zero this batch's colval slab: H*S = 32768 floats -> 8192 float4.
    f32x4* cv4 = reinterpret_cast<f32x4*>(colval + (size_t)b * H_ * S_);
    #pragma unroll
    for (int i = tid; i < (H_ * S_) / 4; i += 256)
        cv4[i] = (f32x4)(0.f);

    // Reduce the NCH partials (L2-resident, 256 KB total).
    const f32x4* pb = partial4 + (size_t)b * NCH * 256;
    f32x4 acc = (f32x4)(0.f);
    #pragma unroll
    for (int c = 0; c < NCH; ++c)
        acc += pb[c * 256 + tid];
    reinterpret_cast<f32x4*>(s_jr)[tid] = acc;
    __syncthreads();

    // anchor[h][j] = (1/K) * sum_r s[j][r] * W[r][h]
    for (int p = tid; p < H_ * K_; p += 256) {
        const int h = p >> 6;
        const int j = p & 63;
        float a = 0.f;
        #pragma unroll
        for (int r = 0; r < R_; ++r)
            a += s_jr[j * R_ + r] * s_W[r * H_ + h];
        s_anchor[p] = a * (1.0f / K_);
    }
    __syncthreads();

    if (tid < H_) {
        const int h = tid;
        float* cvh = colval + ((size_t)b * H_ + h) * S_;
        for (int k = 0; k < K_; ++k) {
            const int c = idx[b * K_ + k];
            cvh[c] = s_anchor[h * K_ + k];
        }
    }
}

// ---------------------------------------------------------------------------
// Kernel B: streaming broadcast with nontemporal stores.
// Block (x=row-chunk, y=bh). Each block loads its 8 KB colval row once
// (2 float4/thread) and writes ROWS_PER_BLOCK rows, 16B/lane coalesced.
// ---------------------------------------------------------------------------
__global__ __launch_bounds__(256) void broadcast_rows_kernel(
    const f32x4* __restrict__ colval4,  // [B*H, S/4]
    f32x4*       __restrict__ out4)     // [B*H, S, S/4]
{
    const int bh   = blockIdx.y;
    const int row0 = blockIdx.x * ROWS_PER_BLOCK;
    const int t    = threadIdx.x;

    const int cvbase = bh * (S_ / 4);            // S/4 = 512
    const f32x4 v0 = colval4[cvbase + t];
    const f32x4 v1 = colval4[cvbase + 256 + t];

    f32x4* base = out4 + ((size_t)bh * S_ + row0) * (S_ / 4);
    #pragma unroll
    for (int r = 0; r < ROWS_PER_BLOCK; ++r) {
        __builtin_nontemporal_store(v0, &base[(size_t)r * (S_ / 4) + t]);
        __builtin_nontemporal_store(v1, &base[(size_t)r * (S_ / 4) + 256 + t]);
    }
}

extern "C" void kernel_launch(void* const* d_in, const int* in_sizes, int n_in,
                              void* d_out, int out_size, void* d_ws, size_t ws_size,
                              hipStream_t stream) {
    const float* adj = (const float*)d_in[0];   // [B,K,K,R] fp32
    const float* W   = (const float*)d_in[1];   // [R,H] fp32
    const int*   idx = (const int*)d_in[2];     // [B,K] int32
    // d_in[3] = seq_l scalar (2048), hardcoded as S_.

    float* out     = (float*)d_out;
    float* colval  = (float*)d_ws;                       // B*H*S fp32 = 512 KB
    float* partial = colval + (size_t)B_ * H_ * S_;      // B*NCH*1024 = 256 KB

    dim3 gA1(B_, NCH);                                   // 64 blocks
    partial_reduce_kernel<<<gA1, 256, 0, stream>>>(
        (const f32x4*)adj, (f32x4*)partial);

    finalize_colval_kernel<<<B_, 256, 0, stream>>>(
        (const f32x4*)partial, W, idx, colval);

    dim3 gB(S_ / ROWS_PER_BLOCK, B_ * H_);               // (128, 64)
    broadcast_rows_kernel<<<gB, 256, 0, stream>>>(
        (const f32x4*)colval, (f32x4*)out);
}

// Round 4
// 199.616 us; speedup vs baseline: 1.0413x; 1.0413x over previous
//
#include <hip/hip_runtime.h>

// Problem constants (fixed-shape bench)
#define B_ 4
#define K_ 64
#define R_ 16
#define H_ 16
#define S_ 2048
#define ROWS_PER_BLOCK 16
#define NCH 16   // i-chunks for partial reduction
#define IPB 4    // i-rows per chunk (NCH*IPB == K_)

typedef float f32x4 __attribute__((ext_vector_type(4)));

// ---------------------------------------------------------------------------
// Kernel A1: partial reduction over i. Grid (B, NCH), 256 thr.
//   partial[b][ch][q] = sum_{i in chunk} adj[b, i, q/R, q%R],  q = 0..1023
// ---------------------------------------------------------------------------
__global__ __launch_bounds__(256) void partial_reduce_kernel(
    const f32x4* __restrict__ adj4,     // [B,K, K*R/4]
    f32x4*       __restrict__ partial4) // [B,NCH, 256]
{
    const int b   = blockIdx.x;
    const int ch  = blockIdx.y;
    const int tid = threadIdx.x;

    const f32x4* base = adj4 + ((size_t)b * K_ + ch * IPB) * (K_ * R_ / 4);
    f32x4 acc = (f32x4)(0.f);
    #pragma unroll
    for (int i = 0; i < IPB; ++i)
        acc += base[i * (K_ * R_ / 4) + tid];
    partial4[((size_t)b * NCH + ch) * 256 + tid] = acc;
}

// ---------------------------------------------------------------------------
// Kernel A2: finalize, one block per (b,h). Grid (B,H), 256 thr.
//   s[j][r]   = sum_ch partial[b][ch][j*R+r]        (redundant per h, L2-hit)
//   anchor[j] = (1/K) * sum_r s[j][r] * W[r][h]
//   colval[b,h,:] = 0; parallel scatter with last-occurrence-wins mask
//   (matches numpy fancy-assignment duplicate semantics).
// ---------------------------------------------------------------------------
__global__ __launch_bounds__(256) void finalize_colval_kernel(
    const f32x4* __restrict__ partial4, // [B,NCH,256]
    const float* __restrict__ W,        // [R,H]
    const int*   __restrict__ idx,      // [B,K]
    float*       __restrict__ colval)   // [B,H,S]
{
    __shared__ float s_jr[K_ * R_];   // s[j][r]
    __shared__ float s_anchor[K_];
    __shared__ int   s_idx[K_];
    __shared__ int   s_win[K_];

    const int b   = blockIdx.x;
    const int h   = blockIdx.y;
    const int tid = threadIdx.x;

    // Reduce the NCH partials (64 KB per batch, L2-resident).
    const f32x4* pb = partial4 + (size_t)b * NCH * 256;
    f32x4 acc = (f32x4)(0.f);
    #pragma unroll
    for (int c = 0; c < NCH; ++c)
        acc += pb[c * 256 + tid];
    reinterpret_cast<f32x4*>(s_jr)[tid] = acc;

    if (tid < K_) s_idx[tid] = idx[b * K_ + tid];

    // Zero this (b,h) colval row: S floats = 512 f32x4.
    f32x4* cv4 = reinterpret_cast<f32x4*>(colval + ((size_t)b * H_ + h) * S_);
    cv4[tid]       = (f32x4)(0.f);
    cv4[tid + 256] = (f32x4)(0.f);
    __syncthreads();

    if (tid < K_) {
        // anchor for this head
        float a = 0.f;
        #pragma unroll
        for (int r = 0; r < R_; ++r)
            a += s_jr[tid * R_ + r] * W[r * H_ + h];
        s_anchor[tid] = a * (1.0f / K_);
        // winner = last occurrence of this index value
        const int c = s_idx[tid];
        int win = 1;
        for (int k2 = tid + 1; k2 < K_; ++k2)
            win &= (s_idx[k2] != c);
        s_win[tid] = win;
    }
    __syncthreads();

    if (tid < K_ && s_win[tid]) {
        colval[((size_t)b * H_ + h) * S_ + s_idx[tid]] = s_anchor[tid];
    }
}

// ---------------------------------------------------------------------------
// Kernel B: streaming broadcast, plain stores (nt-stores measured slower).
// Block (x=row-chunk, y=bh). Each block loads its 8 KB colval row once
// (2 f32x4/thread) and writes ROWS_PER_BLOCK rows, 16B/lane coalesced.
// ---------------------------------------------------------------------------
__global__ __launch_bounds__(256) void broadcast_rows_kernel(
    const f32x4* __restrict__ colval4,  // [B*H, S/4]
    f32x4*       __restrict__ out4)     // [B*H, S, S/4]
{
    const int bh   = blockIdx.y;
    const int row0 = blockIdx.x * ROWS_PER_BLOCK;
    const int t    = threadIdx.x;

    const int cvbase = bh * (S_ / 4);            // S/4 = 512
    const f32x4 v0 = colval4[cvbase + t];
    const f32x4 v1 = colval4[cvbase + 256 + t];

    f32x4* base = out4 + ((size_t)bh * S_ + row0) * (S_ / 4);
    #pragma unroll
    for (int r = 0; r < ROWS_PER_BLOCK; ++r) {
        base[(size_t)r * (S_ / 4) + t]       = v0;
        base[(size_t)r * (S_ / 4) + 256 + t] = v1;
    }
}

extern "C" void kernel_launch(void* const* d_in, const int* in_sizes, int n_in,
                              void* d_out, int out_size, void* d_ws, size_t ws_size,
                              hipStream_t stream) {
    const float* adj = (const float*)d_in[0];   // [B,K,K,R] fp32
    const float* W   = (const float*)d_in[1];   // [R,H] fp32
    const int*   idx = (const int*)d_in[2];     // [B,K] int32
    // d_in[3] = seq_l scalar (2048), hardcoded as S_.

    float* out     = (float*)d_out;
    float* colval  = (float*)d_ws;                       // B*H*S fp32 = 512 KB
    float* partial = colval + (size_t)B_ * H_ * S_;      // B*NCH*1024 = 256 KB

    dim3 gA1(B_, NCH);                                   // 64 blocks
    partial_reduce_kernel<<<gA1, 256, 0, stream>>>(
        (const f32x4*)adj, (f32x4*)partial);

    dim3 gA2(B_, H_);                                    // 64 blocks
    finalize_colval_kernel<<<gA2, 256, 0, stream>>>(
        (const f32x4*)partial, W, idx, colval);

    dim3 gB(S_ / ROWS_PER_BLOCK, B_ * H_);               // (128, 64)
    broadcast_rows_kernel<<<gB, 256, 0, stream>>>(
        (const f32x4*)colval, (f32x4*)out);
}

// Round 5
// 197.000 us; speedup vs baseline: 1.0551x; 1.0133x over previous
//
#include <hip/hip_runtime.h>

// Problem constants (fixed-shape bench)
#define B_ 4
#define K_ 64
#define R_ 16
#define H_ 16
#define S_ 2048
#define ROWS_PER_BLOCK 32
#define NCH 64   // i-chunks for partial reduction (IPB = 1)

typedef float f32x4 __attribute__((ext_vector_type(4)));

// ---------------------------------------------------------------------------
// Kernel A1: partial reduction over i. Grid (B, NCH), 256 thr, IPB=1.
//   partial[b][ch][q] = adj[b, ch, q/R, q%R]  summed later by A2.
// 256 blocks -> full-chip-speed read of the 16.8 MB adj tensor.
// ---------------------------------------------------------------------------
__global__ __launch_bounds__(256) void partial_reduce_kernel(
    const f32x4* __restrict__ adj4,     // [B,K, K*R/4]
    f32x4*       __restrict__ partial4) // [B,NCH, 256]
{
    const int b   = blockIdx.x;
    const int ch  = blockIdx.y;
    const int tid = threadIdx.x;

    partial4[((size_t)b * NCH + ch) * 256 + tid] =
        adj4[((size_t)b * K_ + ch) * (K_ * R_ / 4) + tid];
}

// ---------------------------------------------------------------------------
// Kernel A2: finalize, one block per (b,h). Grid (B,H), 256 thr.
//   s[j][r]   = sum_ch partial[b][ch][j*R+r]        (L2-resident)
//   anchor[j] = (1/K) * sum_r s[j][r] * W[r][h]
//   colval[b,h,:] = 0; parallel scatter, last-occurrence-wins
//   (numpy fancy-assignment duplicate semantics).
// ---------------------------------------------------------------------------
__global__ __launch_bounds__(256) void finalize_colval_kernel(
    const f32x4* __restrict__ partial4, // [B,NCH,256]
    const float* __restrict__ W,        // [R,H]
    const int*   __restrict__ idx,      // [B,K]
    float*       __restrict__ colval)   // [B,H,S]
{
    __shared__ float s_jr[K_ * R_];   // s[j][r]
    __shared__ float s_anchor[K_];
    __shared__ int   s_idx[K_];
    __shared__ int   s_win[K_];

    const int b   = blockIdx.x;
    const int h   = blockIdx.y;
    const int tid = threadIdx.x;

    // Reduce the NCH partials (256 KB per batch, L2-resident).
    const f32x4* pb = partial4 + (size_t)b * NCH * 256;
    f32x4 acc = (f32x4)(0.f);
    #pragma unroll
    for (int c = 0; c < NCH; ++c)
        acc += pb[c * 256 + tid];
    reinterpret_cast<f32x4*>(s_jr)[tid] = acc;

    if (tid < K_) s_idx[tid] = idx[b * K_ + tid];

    // Zero this (b,h) colval row: S floats = 512 f32x4.
    f32x4* cv4 = reinterpret_cast<f32x4*>(colval + ((size_t)b * H_ + h) * S_);
    cv4[tid]       = (f32x4)(0.f);
    cv4[tid + 256] = (f32x4)(0.f);
    __syncthreads();

    if (tid < K_) {
        float a = 0.f;
        #pragma unroll
        for (int r = 0; r < R_; ++r)
            a += s_jr[tid * R_ + r] * W[r * H_ + h];
        s_anchor[tid] = a * (1.0f / K_);
        // winner = last occurrence of this index value
        const int c = s_idx[tid];
        int win = 1;
        for (int k2 = tid + 1; k2 < K_; ++k2)
            win &= (s_idx[k2] != c);
        s_win[tid] = win;
    }
    __syncthreads();

    if (tid < K_ && s_win[tid]) {
        colval[((size_t)b * H_ + h) * S_ + s_idx[tid]] = s_anchor[tid];
    }
}

// ---------------------------------------------------------------------------
// Kernel B: streaming broadcast. 512 threads; each thread owns ONE f32x4
// column slot (whole 8 KB row covered per iteration), walks 32 rows.
// Per wave: one monotone store stream of 1 KB bursts at 8 KB stride.
// Grid (S/ROWS, B*H) = (64, 64) = 4096 blocks x 256 KB each.
// ---------------------------------------------------------------------------
__global__ __launch_bounds__(512) void broadcast_rows_kernel(
    const f32x4* __restrict__ colval4,  // [B*H, S/4]
    f32x4*       __restrict__ out4)     // [B*H, S, S/4]
{
    const int bh   = blockIdx.y;
    const int row0 = blockIdx.x * ROWS_PER_BLOCK;
    const int t    = threadIdx.x;        // 0..511 == S/4

    const f32x4 v = colval4[bh * (S_ / 4) + t];

    f32x4* base = out4 + ((size_t)bh * S_ + row0) * (S_ / 4) + t;
    #pragma unroll
    for (int r = 0; r < ROWS_PER_BLOCK; ++r) {
        base[(size_t)r * (S_ / 4)] = v;
    }
}

extern "C" void kernel_launch(void* const* d_in, const int* in_sizes, int n_in,
                              void* d_out, int out_size, void* d_ws, size_t ws_size,
                              hipStream_t stream) {
    const float* adj = (const float*)d_in[0];   // [B,K,K,R] fp32
    const float* W   = (const float*)d_in[1];   // [R,H] fp32
    const int*   idx = (const int*)d_in[2];     // [B,K] int32
    // d_in[3] = seq_l scalar (2048), hardcoded as S_.

    float* out     = (float*)d_out;
    float* colval  = (float*)d_ws;                       // B*H*S fp32 = 512 KB
    float* partial = colval + (size_t)B_ * H_ * S_;      // B*NCH*1024 = 1 MB

    dim3 gA1(B_, NCH);                                   // 256 blocks
    partial_reduce_kernel<<<gA1, 256, 0, stream>>>(
        (const f32x4*)adj, (f32x4*)partial);

    dim3 gA2(B_, H_);                                    // 64 blocks
    finalize_colval_kernel<<<gA2, 256, 0, stream>>>(
        (const f32x4*)partial, W, idx, colval);

    dim3 gB(S_ / ROWS_PER_BLOCK, B_ * H_);               // (64, 64)
    broadcast_rows_kernel<<<gB, 512, 0, stream>>>(
        (const f32x4*)colval, (f32x4*)out);
}

// Round 6
// 194.267 us; speedup vs baseline: 1.0700x; 1.0141x over previous
//
#include <hip/hip_runtime.h>

// Problem constants (fixed-shape bench)
#define B_ 4
#define K_ 64
#define R_ 16
#define H_ 16
#define S_ 2048
#define ROWS_PER_BLOCK 128   // rows per block in broadcast: grid.x = 16

typedef float f32x4 __attribute__((ext_vector_type(4)));

// ---------------------------------------------------------------------------
// Kernel A: one block per (b,h). Grid (B,H) = 64 blocks, 256 thr.
// adj is only 1 MB total -> every block reads adj[b] (256 KB) straight from
// L2. s[j][r] = sum_i adj[b,i,j,r]; anchor[j] = (1/K) sum_r s[j][r] W[r][h];
// colval[b,h,:] = 0 then parallel scatter with last-occurrence-wins mask
// (numpy fancy-assignment duplicate semantics).
// ---------------------------------------------------------------------------
__global__ __launch_bounds__(256) void finalize_colval_kernel(
    const f32x4* __restrict__ adj4,    // [B*K, 256]  (= [B,K,K,R] /4)
    const float* __restrict__ W,       // [R,H]
    const int*   __restrict__ idx,     // [B,K]
    float*       __restrict__ colval)  // [B,H,S]
{
    __shared__ float s_jr[K_ * R_];   // s[j][r], q = j*R+r flattened
    __shared__ float s_anchor[K_];
    __shared__ int   s_idx[K_];
    __shared__ int   s_win[K_];

    const int b   = blockIdx.x;
    const int h   = blockIdx.y;
    const int tid = threadIdx.x;

    // Column-sum over i: 64 loads at 4 KB stride, coalesced across threads.
    const f32x4* ab = adj4 + (size_t)b * K_ * 256;
    f32x4 acc = (f32x4)(0.f);
    #pragma unroll
    for (int i = 0; i < K_; ++i)
        acc += ab[i * 256 + tid];
    reinterpret_cast<f32x4*>(s_jr)[tid] = acc;

    if (tid < K_) s_idx[tid] = idx[b * K_ + tid];

    // Zero this (b,h) colval row: S floats = 512 f32x4.
    f32x4* cv4 = reinterpret_cast<f32x4*>(colval + ((size_t)b * H_ + h) * S_);
    cv4[tid]       = (f32x4)(0.f);
    cv4[tid + 256] = (f32x4)(0.f);
    __syncthreads();

    if (tid < K_) {
        float a = 0.f;
        #pragma unroll
        for (int r = 0; r < R_; ++r)
            a += s_jr[tid * R_ + r] * W[r * H_ + h];
        s_anchor[tid] = a * (1.0f / K_);
        // winner = last occurrence of this index value
        const int c = s_idx[tid];
        int win = 1;
        for (int k2 = tid + 1; k2 < K_; ++k2)
            win &= (s_idx[k2] != c);
        s_win[tid] = win;
    }
    __syncthreads();

    if (tid < K_ && s_win[tid]) {
        colval[((size_t)b * H_ + h) * S_ + s_idx[tid]] = s_anchor[tid];
    }
}

// ---------------------------------------------------------------------------
// Kernel B: streaming broadcast, exact-residency shape.
// Grid (S/ROWS_PER_BLOCK, B*H) = (16,64) = 1024 blocks x 512 thr
//   = 4 blocks/CU = 32 waves/CU: FULL occupancy in ONE residency generation,
// no block turnover, one colval load per thread, then 128 monotone 16B
// stores at 8 KB stride (per wave: 1 KB bursts, fully coalesced).
// Plain stores (nontemporal measured 10% slower in R3).
// ---------------------------------------------------------------------------
__global__ __launch_bounds__(512) void broadcast_rows_kernel(
    const f32x4* __restrict__ colval4,  // [B*H, S/4]
    f32x4*       __restrict__ out4)     // [B*H, S, S/4]
{
    const int bh   = blockIdx.y;
    const int row0 = blockIdx.x * ROWS_PER_BLOCK;
    const int t    = threadIdx.x;        // 0..511 == S/4

    const f32x4 v = colval4[bh * (S_ / 4) + t];

    f32x4* base = out4 + ((size_t)bh * S_ + row0) * (S_ / 4) + t;
    #pragma unroll 16
    for (int r = 0; r < ROWS_PER_BLOCK; ++r) {
        base[(size_t)r * (S_ / 4)] = v;
    }
}

extern "C" void kernel_launch(void* const* d_in, const int* in_sizes, int n_in,
                              void* d_out, int out_size, void* d_ws, size_t ws_size,
                              hipStream_t stream) {
    const float* adj = (const float*)d_in[0];   // [B,K,K,R] fp32 (1 MB)
    const float* W   = (const float*)d_in[1];   // [R,H] fp32
    const int*   idx = (const int*)d_in[2];     // [B,K] int32
    // d_in[3] = seq_l scalar (2048), hardcoded as S_.

    float* out    = (float*)d_out;
    float* colval = (float*)d_ws;               // B*H*S fp32 = 512 KB scratch

    dim3 gA(B_, H_);                            // 64 blocks
    finalize_colval_kernel<<<gA, 256, 0, stream>>>(
        (const f32x4*)adj, W, idx, colval);

    dim3 gB(S_ / ROWS_PER_BLOCK, B_ * H_);      // (16, 64) = 1024 blocks
    broadcast_rows_kernel<<<gB, 512, 0, stream>>>(
        (const f32x4*)colval, (f32x4*)out);
}